// Round 2
// baseline (569.993 us; speedup 1.0000x reference)
//
#include <hip/hip_runtime.h>
#include <hip/hip_bf16.h>

// ---------------------------------------------------------------------------
// SingleHeadAttention: b=8, t=2048, e=1024. I/O = float32.
//   Q = (q @ Wq^T)/e^0.25 ; K = (k @ Wk^T)/e^0.25 ; V = v @ Wv^T
//   S = Q K^T (causal) ; P = softmax(S) ; O = P V
// bf16 MFMA internals, f32 accumulate, f32 output.
//
// Round-7: 2-phase double-buffered staging (T3 minimum recipe) in all GEMMs.
// Round-6 showed the 1-phase stage->drain->compute loop is latency-bound
// (MfmaUtil 22% at BOTH BK=32/64): every K-step drains vmcnt(0) cold.
// Now: stage tile t+1 into buf^1 BEFORE computing tile t; single
// __syncthreads() per K-step publishes the staged tile and protects reuse.
// proj: back to BK=32 (verbatim round-5 addressing), 48 KB dbuf, plus
// flattened column-fastest grid with bijective XCD chunking so the 8 blocks
// sharing an A f32 panel run adjacently on one XCD (A re-reads -> L2 hits;
// round-6 FETCH was 459 MB vs ~210 ideal).
// score/out: dbuf gemm_tile64 (64 KB LDS, 2 blocks/CU).
//  - ws: [Q][K][Vt][S]; bf16 weights alias the dead S region during proj.
// ---------------------------------------------------------------------------

typedef short short8 __attribute__((ext_vector_type(8)));   // 8 x bf16
typedef float f32x4 __attribute__((ext_vector_type(4)));
typedef int   int4v __attribute__((ext_vector_type(4)));

static constexpr int B_ = 8;
static constexpr int T_ = 2048;
static constexpr int E_ = 1024;

__device__ __forceinline__ float bf2f(ushort u) {
    union { unsigned int i; float f; } x; x.i = ((unsigned int)u) << 16; return x.f;
}
__device__ __forceinline__ ushort f2bf(float f) {
    union { float f; unsigned int i; } x; x.f = f;
    unsigned int r = x.i + 0x7fffu + ((x.i >> 16) & 1u);   // RNE
    return (ushort)(r >> 16);
}
// packed f32x8 -> bf16x8 (RNE)
__device__ __forceinline__ short8 cvt8(f32x4 a, f32x4 b) {
    short8 r;
    union { __hip_bfloat162 h; unsigned int u; } p;
    unsigned int* ru = (unsigned int*)&r;
    p.h = __float22bfloat162_rn(make_float2(a[0], a[1])); ru[0] = p.u;
    p.h = __float22bfloat162_rn(make_float2(a[2], a[3])); ru[1] = p.u;
    p.h = __float22bfloat162_rn(make_float2(b[0], b[1])); ru[2] = p.u;
    p.h = __float22bfloat162_rn(make_float2(b[2], b[3])); ru[3] = p.u;
    return r;
}

// async 16B global -> LDS; lds base wave-uniform, lane i lands at +16*i.
__device__ __forceinline__ void async16(const ushort* g, ushort* l) {
    __builtin_amdgcn_global_load_lds(
        (const __attribute__((address_space(1))) unsigned int*)g,
        (__attribute__((address_space(3))) unsigned int*)l, 16, 0, 0);
}
__device__ __forceinline__ void async16f(const float* g, float* l) {
    __builtin_amdgcn_global_load_lds(
        (const __attribute__((address_space(1))) unsigned int*)g,
        (__attribute__((address_space(3))) unsigned int*)l, 16, 0, 0);
}

// ---------------------------------------------------------------------------
// 2-phase double-buffered BK=64 NT GEMM tile:
//   C[128x128] += A[128xK] * B[128xK]^T, bf16, K contiguous.
// Per-buffer LDS 128x64 per operand (16 KB); x2 buffers = 64 KB total.
// Row = 8 granules of 16B; LDS (r,g) holds global (r, g ^ (r&7)).
// Loop: stage tile ks+1 into buf^1 (loads fly during compute), compute
// tile ks from buf, then ONE __syncthreads (vmcnt0+lgkm0+barrier).
__device__ __forceinline__ void gemm_tile64_db(const ushort* __restrict__ A, int lda,
                                               const ushort* __restrict__ Bm, int ldb,
                                               int ksteps, f32x4 (&acc)[4][4],
                                               ushort* As, ushort* Bs)
{
    const int tid = threadIdx.x, lane = tid & 63, wave = tid >> 6;
    const int wr = (wave >> 1) * 64, wc = (wave & 1) * 64;
    const int srow = lane >> 3;                     // row within 8-row chunk
    const int scol = ((lane & 7) ^ srow) * 8;       // swizzled source col (elems)
    const int frow = lane & 15, q4 = lane >> 4;

    // prologue: stage tile 0 into buffer 0
#pragma unroll
    for (int j = 0; j < 4; ++j) {
        const int c = wave * 4 + j;                 // 16 chunks per operand
        const int grow = c * 8 + srow;
        async16(A  + (size_t)grow * lda + scol, As + c * 512);
        async16(Bm + (size_t)grow * ldb + scol, Bs + c * 512);
    }
    __syncthreads();                                // tile 0 resident

    int cur = 0;
    for (int ks = 0; ks < ksteps; ++ks) {
        // stage next tile into the other buffer; loads overlap compute
        if (ks + 1 < ksteps) {
            const int k0 = (ks + 1) * 64;
            const int nb = (cur ^ 1) * 8192;
#pragma unroll
            for (int j = 0; j < 4; ++j) {
                const int c = wave * 4 + j;
                const int grow = c * 8 + srow;
                async16(A  + (size_t)grow * lda + k0 + scol, As + nb + c * 512);
                async16(Bm + (size_t)grow * ldb + k0 + scol, Bs + nb + c * 512);
            }
        }
        // compute current tile
        const ushort* Ab = As + cur * 8192;
        const ushort* Bb = Bs + cur * 8192;
        short8 af[4][2], bf[4][2];
#pragma unroll
        for (int i = 0; i < 4; ++i) {
            const int ra = wr + i * 16 + frow;
            const int rb = wc + i * 16 + frow;
            const int sw = frow & 7;
#pragma unroll
            for (int kk = 0; kk < 2; ++kk) {
                const int g = (kk * 4 + q4) ^ sw;
                af[i][kk] = *(const short8*)(Ab + ra * 64 + g * 8);
                bf[i][kk] = *(const short8*)(Bb + rb * 64 + g * 8);
            }
        }
#pragma unroll
        for (int kk = 0; kk < 2; ++kk)
#pragma unroll
            for (int mi = 0; mi < 4; ++mi)
#pragma unroll
                for (int ni = 0; ni < 4; ++ni)
                    acc[mi][ni] = __builtin_amdgcn_mfma_f32_16x16x32_bf16(
                        af[mi][kk], bf[ni][kk], acc[mi][ni], 0, 0, 0);
        __syncthreads();   // next tile published; all waves done reading cur
        cur ^= 1;
    }
}

// ---------------------------------------------------------------------------
// Weight converter: three 1024x1024 f32 -> bf16 (grid.y = 3).
__global__ __launch_bounds__(256)
void cvtW_kernel(const float* __restrict__ w0, const float* __restrict__ w1,
                 const float* __restrict__ w2, ushort* __restrict__ d)
{
    const float* s = blockIdx.y == 0 ? w0 : (blockIdx.y == 1 ? w1 : w2);
    ushort* dd = d + (size_t)blockIdx.y * E_ * E_;
    const int idx = (blockIdx.x * 256 + threadIdx.x) * 8;
    f32x4 a = *(const f32x4*)(s + idx);
    f32x4 b = *(const f32x4*)(s + idx + 4);
    *(short8*)(dd + idx) = cvt8(a, b);
}

// ---------------------------------------------------------------------------
// Stage 1: all three projections, one dispatch. grid (3072). BK=32, 2-phase.
// Flattened block id, XCD-chunked (3072 % 8 == 0 -> bijective), column-
// fastest so the 8 blocks sharing one A f32 row-panel run adjacently on the
// same XCD (A re-reads hit that XCD's L2).
// A tile: 128x32 f32 (16 KB/buf), 8 granules/row, swz g^(r&7).
// B tile: 128x32 bf16 (8 KB/buf), 4 granules/row, swz g^((r>>1)&3).
__global__ __launch_bounds__(256, 2)
void proj_kernel(const float* __restrict__ q, const float* __restrict__ k,
                 const float* __restrict__ v, const ushort* __restrict__ Wb,
                 ushort* __restrict__ Q, ushort* __restrict__ Kp,
                 ushort* __restrict__ Vt)
{
    __shared__ float  Asf[2 * 128 * 32];   // 32 KB
    __shared__ ushort Bs[2 * 128 * 32];    // 16 KB

    const int bid = blockIdx.x;
    const int n   = (bid & 7) * 384 + (bid >> 3);   // XCD chunk (3072/8=384)
    const int z   = n >> 10;                         // 0..2 : q,k,v
    const int rem = n & 1023;
    const int by  = rem & 7;                         // W col-block (fastest)
    const int bx  = rem >> 3;                        // A row-panel

    const float* A = (z == 0 ? q : (z == 1 ? k : v)) + (size_t)bx * 128 * E_;
    const ushort* W = Wb + (size_t)z * E_ * E_ + (size_t)by * 128 * E_;

    const int tid = threadIdx.x, lane = tid & 63, wave = tid >> 6;
    const int wr = (wave >> 1) * 64, wc = (wave & 1) * 64;
    // A staging: chunk = 8 rows x 32 f32; lane -> row lane>>3, src granule ^row
    const int sArow = lane >> 3;
    const int sAcol = ((lane & 7) ^ sArow) * 4;
    // B staging: chunk = 16 rows x 32 bf16; lane -> row lane>>2, src gran ^(row>>1)
    const int sBrow = lane >> 2;
    const int sBcol = ((lane & 3) ^ ((lane >> 3) & 3)) * 8;
    const int frow = lane & 15, q4 = lane >> 4;

    f32x4 acc[4][4];
#pragma unroll
    for (int i = 0; i < 4; ++i)
#pragma unroll
        for (int j = 0; j < 4; ++j) acc[i][j] = (f32x4){0.f, 0.f, 0.f, 0.f};

    // prologue: stage tile 0 -> buffer 0
#pragma unroll
    for (int j = 0; j < 4; ++j) {
        const int c = wave * 4 + j;
        async16f(A + (size_t)(c * 8 + sArow) * E_ + sAcol, Asf + c * 256);
    }
#pragma unroll
    for (int j = 0; j < 2; ++j) {
        const int c = wave * 2 + j;
        async16(W + (size_t)(c * 16 + sBrow) * E_ + sBcol, Bs + c * 512);
    }
    __syncthreads();

    int cur = 0;
    const int nt = E_ / 32;
    for (int ks = 0; ks < nt; ++ks) {
        // stage tile ks+1 into other buffer (overlaps compute below)
        if (ks + 1 < nt) {
            const int k0 = (ks + 1) * 32;
            const int na = (cur ^ 1) * 4096, nb = (cur ^ 1) * 4096;
#pragma unroll
            for (int j = 0; j < 4; ++j) {
                const int c = wave * 4 + j;
                async16f(A + (size_t)(c * 8 + sArow) * E_ + k0 + sAcol,
                         Asf + na + c * 256);
            }
#pragma unroll
            for (int j = 0; j < 2; ++j) {
                const int c = wave * 2 + j;
                async16(W + (size_t)(c * 16 + sBrow) * E_ + k0 + sBcol,
                        Bs + nb + c * 512);
            }
        }
        // compute current tile
        const float*  Ab = Asf + cur * 4096;
        const ushort* Bb = Bs  + cur * 4096;
        short8 af[4], bf[4];
#pragma unroll
        for (int i = 0; i < 4; ++i) {
            const int R = wr + i * 16 + frow;
            const int g0 = (q4 * 2) ^ (frow & 7);
            const int g1 = g0 ^ 1;
            f32x4 lo = *(const f32x4*)(Ab + R * 32 + g0 * 4);
            f32x4 hi = *(const f32x4*)(Ab + R * 32 + g1 * 4);
            af[i] = cvt8(lo, hi);
        }
#pragma unroll
        for (int i = 0; i < 4; ++i) {
            const int R = wc + i * 16 + frow;
            const int g = q4 ^ ((frow >> 1) & 3);
            bf[i] = *(const short8*)(Bb + R * 32 + g * 8);
        }
#pragma unroll
        for (int mi = 0; mi < 4; ++mi)
#pragma unroll
            for (int ni = 0; ni < 4; ++ni)
                acc[mi][ni] = __builtin_amdgcn_mfma_f32_16x16x32_bf16(
                    af[mi], bf[ni], acc[mi][ni], 0, 0, 0);
        __syncthreads();
        cur ^= 1;
    }

    const float scale = (z == 2) ? 1.0f : 0.17677669529663687f;  // 1/e^(1/4)
    if (z < 2) {
        ushort* D = (z == 0 ? Q : Kp);
#pragma unroll
        for (int mi = 0; mi < 4; ++mi)
#pragma unroll
            for (int r = 0; r < 4; ++r) {
                const int row = bx * 128 + wr + mi * 16 + (lane >> 4) * 4 + r;
#pragma unroll
                for (int ni = 0; ni < 4; ++ni) {
                    const int col = by * 128 + wc + ni * 16 + (lane & 15);
                    D[(size_t)row * E_ + col] = f2bf(acc[mi][ni][r] * scale);
                }
            }
    } else {
#pragma unroll
        for (int mi = 0; mi < 4; ++mi)
#pragma unroll
            for (int r = 0; r < 4; ++r) {
                const int rowg = bx * 128 + wr + mi * 16 + (lane >> 4) * 4 + r;
                const int bb = rowg >> 11, tl = rowg & 2047;
#pragma unroll
                for (int ni = 0; ni < 4; ++ni) {
                    const int col = by * 128 + wc + ni * 16 + (lane & 15);
                    Vt[(size_t)bb * E_ * T_ + (size_t)col * T_ + tl] = f2bf(acc[mi][ni][r]);
                }
            }
    }
}

// ---------------------------------------------------------------------------
// Stage 2: S = Q K^T causal. Compact lower-triangle grid (136, 8), XCD-chunked
// (136 % 8 == 0 -> bijective) so same-br runs (sharing a Q panel) stay on one
// XCD.
__global__ __launch_bounds__(256, 2)
void score_kernel(const ushort* __restrict__ Q, const ushort* __restrict__ K,
                  ushort* __restrict__ S)
{
    __shared__ ushort As[2 * 128 * 64];   // 32 KB
    __shared__ ushort Bs[2 * 128 * 64];   // 32 KB
    const int b = blockIdx.y;
    const int t = (blockIdx.x & 7) * 17 + (blockIdx.x >> 3);   // 136/8 = 17
    int br = (int)((sqrtf(8.0f * t + 1.0f) - 1.0f) * 0.5f);
    while ((br + 1) * (br + 2) / 2 <= t) ++br;
    while (br * (br + 1) / 2 > t) --br;
    const int bc = t - br * (br + 1) / 2;

    const ushort* A  = Q + ((size_t)b * T_ + br * 128) * E_;
    const ushort* Bm = K + ((size_t)b * T_ + bc * 128) * E_;

    f32x4 acc[4][4];
#pragma unroll
    for (int i = 0; i < 4; ++i)
#pragma unroll
        for (int j = 0; j < 4; ++j) acc[i][j] = (f32x4){0.f, 0.f, 0.f, 0.f};

    gemm_tile64_db(A, E_, Bm, E_, E_ / 64, acc, As, Bs);

    const int lane = threadIdx.x & 63, wave = threadIdx.x >> 6;
    const int wr = (wave >> 1) * 64, wc = (wave & 1) * 64;
    ushort* Sb = S + (size_t)b * T_ * T_;
#pragma unroll
    for (int mi = 0; mi < 4; ++mi)
#pragma unroll
        for (int r = 0; r < 4; ++r) {
            const int row = br * 128 + wr + mi * 16 + (lane >> 4) * 4 + r;
#pragma unroll
            for (int ni = 0; ni < 4; ++ni) {
                const int col = bc * 128 + wc + ni * 16 + (lane & 15);
                float val = acc[mi][ni][r];
                if (col > row) val = -1e30f;
                Sb[(size_t)row * T_ + col] = f2bf(val);
            }
        }
}

// ---------------------------------------------------------------------------
// Stage 3: row softmax in place, 16B vector I/O. One block per row.
__global__ __launch_bounds__(256)
void softmax_kernel(ushort* __restrict__ S)
{
    const int gr = blockIdx.x;
    const int b = gr >> 11, i = gr & 2047;
    ushort* row = S + (size_t)b * T_ * T_ + (size_t)i * T_;
    const int Lpad = ((i >> 7) + 1) * 128;
    const int tid = threadIdx.x, lane = tid & 63, wave = tid >> 6;
    __shared__ float red[4];

    const int j0 = tid * 8;
    const bool act = j0 < Lpad;
    float xv[8];
    if (act) {
        int4v dv = *(const int4v*)(row + j0);
        const ushort* u = (const ushort*)&dv;
#pragma unroll
        for (int t = 0; t < 8; ++t) xv[t] = bf2f(u[t]);
    }

    float m = -1e30f;
    if (act)
#pragma unroll
        for (int t = 0; t < 8; ++t) m = fmaxf(m, xv[t]);
#pragma unroll
    for (int o = 32; o; o >>= 1) m = fmaxf(m, __shfl_xor(m, o, 64));
    if (lane == 0) red[wave] = m;
    __syncthreads();
    m = fmaxf(fmaxf(red[0], red[1]), fmaxf(red[2], red[3]));
    __syncthreads();

    float s = 0.f;
    if (act)
#pragma unroll
        for (int t = 0; t < 8; ++t) { xv[t] = __expf(xv[t] - m); s += xv[t]; }
#pragma unroll
    for (int o = 32; o; o >>= 1) s += __shfl_xor(s, o, 64);
    if (lane == 0) red[wave] = s;
    __syncthreads();
    s = red[0] + red[1] + red[2] + red[3];
    const float inv = 1.0f / s;

    if (act) {
        int4v dv;
        ushort* u = (ushort*)&dv;
#pragma unroll
        for (int t = 0; t < 8; ++t) u[t] = f2bf(xv[t] * inv);
        *(int4v*)(row + j0) = dv;
    }
}

// ---------------------------------------------------------------------------
// Stage 4: O = P @ V via V^T (NT, BK=64, 2-phase). grid (8, 16, 8). f32 out.
// br reversed so the longest causal blocks (br=15, 32 ksteps) dispatch first.
__global__ __launch_bounds__(256, 2)
void out_kernel(const ushort* __restrict__ P, const ushort* __restrict__ Vt,
                float* __restrict__ O)
{
    __shared__ ushort As[2 * 128 * 64];   // 32 KB
    __shared__ ushort Bs[2 * 128 * 64];   // 32 KB
    const int bc = blockIdx.x, b = blockIdx.z;
    const int br = (int)gridDim.y - 1 - (int)blockIdx.y;   // longest first
    const ushort* A  = P  + (size_t)b * T_ * T_ + (size_t)(br * 128) * T_;
    const ushort* Bm = Vt + (size_t)b * E_ * T_ + (size_t)(bc * 128) * T_;
    const int ksteps = (br + 1) * 2;   // causal K-limit, BK=64

    f32x4 acc[4][4];
#pragma unroll
    for (int i = 0; i < 4; ++i)
#pragma unroll
        for (int j = 0; j < 4; ++j) acc[i][j] = (f32x4){0.f, 0.f, 0.f, 0.f};

    gemm_tile64_db(A, T_, Bm, T_, ksteps, acc, As, Bs);

    const int lane = threadIdx.x & 63, wave = threadIdx.x >> 6;
    const int wr = (wave >> 1) * 64, wc = (wave & 1) * 64;
    float* Ob = O + (size_t)b * T_ * E_;
#pragma unroll
    for (int mi = 0; mi < 4; ++mi)
#pragma unroll
        for (int r = 0; r < 4; ++r) {
            const int row = br * 128 + wr + mi * 16 + (lane >> 4) * 4 + r;
#pragma unroll
            for (int ni = 0; ni < 4; ++ni) {
                const int col = bc * 128 + wc + ni * 16 + (lane & 15);
                Ob[(size_t)row * E_ + col] = acc[mi][ni][r];
            }
        }
}

// ---------------------------------------------------------------------------
extern "C" void kernel_launch(void* const* d_in, const int* in_sizes, int n_in,
                              void* d_out, int out_size, void* d_ws, size_t ws_size,
                              hipStream_t stream)
{
    const float* q  = (const float*)d_in[0];
    const float* k  = (const float*)d_in[1];
    const float* v  = (const float*)d_in[2];
    const float* Wq = (const float*)d_in[3];
    const float* Wk = (const float*)d_in[4];
    const float* Wv = (const float*)d_in[5];
    float* out = (float*)d_out;

    const size_t nQKV = (size_t)B_ * T_ * E_;      // 16,777,216 elems
    const size_t nW   = (size_t)E_ * E_;
    ushort* Q  = (ushort*)d_ws;
    ushort* K  = Q + nQKV;
    ushort* Vt = K + nQKV;
    ushort* S  = Vt + nQKV;                        // 67 MB
    ushort* Wb = S;                                // weights alias dead S region

    cvtW_kernel<<<dim3(nW / 2048, 3), 256, 0, stream>>>(Wq, Wk, Wv, Wb);
    proj_kernel<<<dim3(3072), 256, 0, stream>>>(q, k, v, Wb, Q, K, Vt);
    score_kernel<<<dim3(136, B_), 256, 0, stream>>>(Q, K, S);
    softmax_kernel<<<dim3(B_ * T_), 256, 0, stream>>>(S);
    out_kernel<<<dim3(E_ / 128, T_ / 128, B_), 256, 0, stream>>>(S, Vt, out);
}

// Round 3
// 482.729 us; speedup vs baseline: 1.1808x; 1.1808x over previous
//
#include <hip/hip_runtime.h>
#include <hip/hip_bf16.h>

// ---------------------------------------------------------------------------
// SingleHeadAttention: b=8, t=2048, e=1024. I/O = float32.
//   Q = (q @ Wq^T)/e^0.25 ; K = (k @ Wk^T)/e^0.25 ; V = v @ Wv^T
//   S = Q K^T (causal) ; P = softmax(S) ; O = P V
// bf16 MFMA internals, f32 accumulate, f32 output.
//
// Round-8: recombine the proven pieces from rounds 6/7.
//  - ALL GEMMs back to the 1-phase stage->drain->compute structure (the
//    __syncthreads double-buffer of round-7 forced a conservative vmcnt(0)
//    before the ds_reads -> full serialization, 292us proj).
//  - proj keeps round-7's flattened column-fastest XCD-chunked grid, which
//    cut FETCH 450->133 MB (A-panel and W re-reads now L2/L3-local). With
//    the 1-phase loop the per-K-step vmcnt(0) drain is bounded by load
//    latency: L2-hit (~200cy) instead of HBM (~900cy).
//  - proj BK=64 (round-6 body): A 128x64 f32 staged swizzled, B 128x64 bf16.
//  - score: compact triangle grid, XCD-chunked (136 = 8*17, bijective).
//  - out: longest causal blocks dispatch first.
//  - ws: [Q][K][Vt][S]; bf16 weights alias the dead S region during proj.
// ---------------------------------------------------------------------------

typedef short short8 __attribute__((ext_vector_type(8)));   // 8 x bf16
typedef float f32x4 __attribute__((ext_vector_type(4)));
typedef int   int4v __attribute__((ext_vector_type(4)));

static constexpr int B_ = 8;
static constexpr int T_ = 2048;
static constexpr int E_ = 1024;

__device__ __forceinline__ float bf2f(ushort u) {
    union { unsigned int i; float f; } x; x.i = ((unsigned int)u) << 16; return x.f;
}
__device__ __forceinline__ ushort f2bf(float f) {
    union { float f; unsigned int i; } x; x.f = f;
    unsigned int r = x.i + 0x7fffu + ((x.i >> 16) & 1u);   // RNE
    return (ushort)(r >> 16);
}
// packed f32x8 -> bf16x8 (RNE)
__device__ __forceinline__ short8 cvt8(f32x4 a, f32x4 b) {
    short8 r;
    union { __hip_bfloat162 h; unsigned int u; } p;
    unsigned int* ru = (unsigned int*)&r;
    p.h = __float22bfloat162_rn(make_float2(a[0], a[1])); ru[0] = p.u;
    p.h = __float22bfloat162_rn(make_float2(a[2], a[3])); ru[1] = p.u;
    p.h = __float22bfloat162_rn(make_float2(b[0], b[1])); ru[2] = p.u;
    p.h = __float22bfloat162_rn(make_float2(b[2], b[3])); ru[3] = p.u;
    return r;
}

// async 16B global -> LDS; lds base wave-uniform, lane i lands at +16*i.
__device__ __forceinline__ void async16(const ushort* g, ushort* l) {
    __builtin_amdgcn_global_load_lds(
        (const __attribute__((address_space(1))) unsigned int*)g,
        (__attribute__((address_space(3))) unsigned int*)l, 16, 0, 0);
}
__device__ __forceinline__ void async16f(const float* g, float* l) {
    __builtin_amdgcn_global_load_lds(
        (const __attribute__((address_space(1))) unsigned int*)g,
        (__attribute__((address_space(3))) unsigned int*)l, 16, 0, 0);
}

// ---------------------------------------------------------------------------
// BK=64 NT GEMM tile: C[128x128] += A[128xK] * B[128xK]^T, bf16, K contig.
// LDS 128x64 per operand (16 KB). Row = 8 granules of 16B; LDS (r,g) holds
// global (r, g ^ (r&7)) -> conflict-free b128 fragment reads (2-way max).
// 1-phase: stage -> barrier(drain) -> compute -> barrier.
__device__ __forceinline__ void gemm_tile64(const ushort* __restrict__ A, int lda,
                                            const ushort* __restrict__ Bm, int ldb,
                                            int ksteps, f32x4 (&acc)[4][4],
                                            ushort* As, ushort* Bs)
{
    const int tid = threadIdx.x, lane = tid & 63, wave = tid >> 6;
    const int wr = (wave >> 1) * 64, wc = (wave & 1) * 64;
    const int srow = lane >> 3;                     // row within 8-row chunk
    const int scol = ((lane & 7) ^ srow) * 8;       // swizzled source col (elems)
    const int frow = lane & 15, q4 = lane >> 4;

    for (int ks = 0; ks < ksteps; ++ks) {
        const int k0 = ks * 64;
        __syncthreads();   // prior iter's ds_reads complete before overwrite
#pragma unroll
        for (int j = 0; j < 4; ++j) {
            const int c = wave * 4 + j;             // 16 chunks per operand
            const int grow = c * 8 + srow;
            async16(A  + (size_t)grow * lda + k0 + scol, As + c * 512);
            async16(Bm + (size_t)grow * ldb + k0 + scol, Bs + c * 512);
        }
        __syncthreads();   // drains vmcnt(0)

        short8 af[4][2], bf[4][2];
#pragma unroll
        for (int i = 0; i < 4; ++i) {
            const int ra = wr + i * 16 + frow;
            const int rb = wc + i * 16 + frow;
            const int sw = frow & 7;
#pragma unroll
            for (int kk = 0; kk < 2; ++kk) {
                const int g = (kk * 4 + q4) ^ sw;
                af[i][kk] = *(const short8*)(As + ra * 64 + g * 8);
                bf[i][kk] = *(const short8*)(Bs + rb * 64 + g * 8);
            }
        }
#pragma unroll
        for (int kk = 0; kk < 2; ++kk)
#pragma unroll
            for (int mi = 0; mi < 4; ++mi)
#pragma unroll
                for (int ni = 0; ni < 4; ++ni)
                    acc[mi][ni] = __builtin_amdgcn_mfma_f32_16x16x32_bf16(
                        af[mi][kk], bf[ni][kk], acc[mi][ni], 0, 0, 0);
    }
}

// ---------------------------------------------------------------------------
// Weight converter: three 1024x1024 f32 -> bf16 (grid.y = 3).
__global__ __launch_bounds__(256)
void cvtW_kernel(const float* __restrict__ w0, const float* __restrict__ w1,
                 const float* __restrict__ w2, ushort* __restrict__ d)
{
    const float* s = blockIdx.y == 0 ? w0 : (blockIdx.y == 1 ? w1 : w2);
    ushort* dd = d + (size_t)blockIdx.y * E_ * E_;
    const int idx = (blockIdx.x * 256 + threadIdx.x) * 8;
    f32x4 a = *(const f32x4*)(s + idx);
    f32x4 b = *(const f32x4*)(s + idx + 4);
    *(short8*)(dd + idx) = cvt8(a, b);
}

// ---------------------------------------------------------------------------
// Stage 1: all three projections, one dispatch. grid (3072). BK=64, 1-phase.
// Flattened block id, XCD-chunked (3072 % 8 == 0 -> bijective), column-
// fastest so the 8 blocks sharing one A f32 row-panel run adjacently on the
// same XCD (A re-reads hit that XCD's L2; round-7 measured FETCH 133 MB).
// A tile: 128x64 f32 (32 KB), 16 granules/row of 16B, swz g^(r&7).
// B tile: 128x64 bf16 (16 KB), 8 granules/row, swz g^(r&7).
__global__ __launch_bounds__(256, 2)
void proj_kernel(const float* __restrict__ q, const float* __restrict__ k,
                 const float* __restrict__ v, const ushort* __restrict__ Wb,
                 ushort* __restrict__ Q, ushort* __restrict__ Kp,
                 ushort* __restrict__ Vt)
{
    __shared__ float  Asf[128 * 64];    // 32 KB
    __shared__ ushort Bs[128 * 64];     // 16 KB

    const int bid = blockIdx.x;
    const int n   = (bid & 7) * 384 + (bid >> 3);   // XCD chunk (3072/8=384)
    const int z   = n >> 10;                         // 0..2 : q,k,v
    const int rem = n & 1023;
    const int by  = rem & 7;                         // W col-block (fastest)
    const int bx  = rem >> 3;                        // A row-panel

    const float* A = (z == 0 ? q : (z == 1 ? k : v)) + (size_t)bx * 128 * E_;
    const ushort* W = Wb + (size_t)z * E_ * E_ + (size_t)by * 128 * E_;

    const int tid = threadIdx.x, lane = tid & 63, wave = tid >> 6;
    const int wr = (wave >> 1) * 64, wc = (wave & 1) * 64;
    // A staging: chunk = 4 rows x 64 f32 (1024B); lane -> row lane>>4,
    //            LDS granule lane&15, source granule (lane&15)^(row&7).
    const int aRowIn = lane >> 4;
    // B staging: chunk = 8 rows x 64 bf16 (1024B); lane -> row lane>>3,
    //            LDS granule lane&7, source granule (lane&7)^(row&7).
    const int bRowIn = lane >> 3;
    const int frow = lane & 15, q4 = lane >> 4;

    f32x4 acc[4][4];
#pragma unroll
    for (int i = 0; i < 4; ++i)
#pragma unroll
        for (int j = 0; j < 4; ++j) acc[i][j] = (f32x4){0.f, 0.f, 0.f, 0.f};

    for (int ks = 0; ks < E_ / 64; ++ks) {
        const int k0 = ks * 64;
        __syncthreads();
        // A: 8 chunks per wave (32 chunks of 4 rows)
#pragma unroll
        for (int j = 0; j < 8; ++j) {
            const int c = wave * 8 + j;
            const int row = c * 4 + aRowIn;
            const int sg = (lane & 15) ^ (row & 7);
            async16f(A + (size_t)row * E_ + k0 + sg * 4, Asf + c * 256);
        }
        // B: 4 chunks per wave (16 chunks of 8 rows)
#pragma unroll
        for (int j = 0; j < 4; ++j) {
            const int c = wave * 4 + j;
            const int row = c * 8 + bRowIn;
            const int sg = (lane & 7) ^ (row & 7);
            async16(W + (size_t)row * E_ + k0 + sg * 8, Bs + c * 512);
        }
        __syncthreads();   // drains vmcnt(0)

#pragma unroll
        for (int kk = 0; kk < 2; ++kk) {
            short8 af[4], bf[4];
#pragma unroll
            for (int i = 0; i < 4; ++i) {
                const int Ra = wr + i * 16 + frow;
                const int sw = frow & 7;           // (Ra & 7) since wr,i*16 are x8
                const int g0 = (kk * 8 + q4 * 2) ^ sw;
                const int g1 = g0 ^ 1;             // base is even -> +1 flips bit0
                f32x4 lo = *(const f32x4*)(Asf + Ra * 64 + g0 * 4);
                f32x4 hi = *(const f32x4*)(Asf + Ra * 64 + g1 * 4);
                af[i] = cvt8(lo, hi);
                const int Rb = wc + i * 16 + frow;
                const int gb = (kk * 4 + q4) ^ sw;
                bf[i] = *(const short8*)(Bs + Rb * 64 + gb * 8);
            }
#pragma unroll
            for (int mi = 0; mi < 4; ++mi)
#pragma unroll
                for (int ni = 0; ni < 4; ++ni)
                    acc[mi][ni] = __builtin_amdgcn_mfma_f32_16x16x32_bf16(
                        af[mi], bf[ni], acc[mi][ni], 0, 0, 0);
        }
    }

    const float scale = (z == 2) ? 1.0f : 0.17677669529663687f;  // 1/e^(1/4)
    if (z < 2) {
        ushort* D = (z == 0 ? Q : Kp);
#pragma unroll
        for (int mi = 0; mi < 4; ++mi)
#pragma unroll
            for (int r = 0; r < 4; ++r) {
                const int row = bx * 128 + wr + mi * 16 + (lane >> 4) * 4 + r;
#pragma unroll
                for (int ni = 0; ni < 4; ++ni) {
                    const int col = by * 128 + wc + ni * 16 + (lane & 15);
                    D[(size_t)row * E_ + col] = f2bf(acc[mi][ni][r] * scale);
                }
            }
    } else {
#pragma unroll
        for (int mi = 0; mi < 4; ++mi)
#pragma unroll
            for (int r = 0; r < 4; ++r) {
                const int rowg = bx * 128 + wr + mi * 16 + (lane >> 4) * 4 + r;
                const int bb = rowg >> 11, tl = rowg & 2047;
#pragma unroll
                for (int ni = 0; ni < 4; ++ni) {
                    const int col = by * 128 + wc + ni * 16 + (lane & 15);
                    Vt[(size_t)bb * E_ * T_ + (size_t)col * T_ + tl] = f2bf(acc[mi][ni][r]);
                }
            }
    }
}

// ---------------------------------------------------------------------------
// Stage 2: S = Q K^T causal. Compact lower-triangle grid (136, 8), XCD-chunked
// (136 = 8*17, bijective) so same-br runs (sharing a Q panel) stay on one XCD.
__global__ __launch_bounds__(256, 2)
void score_kernel(const ushort* __restrict__ Q, const ushort* __restrict__ K,
                  ushort* __restrict__ S)
{
    __shared__ ushort As[128 * 64];
    __shared__ ushort Bs[128 * 64];
    const int b = blockIdx.y;
    const int t = (blockIdx.x & 7) * 17 + (blockIdx.x >> 3);   // 136/8 = 17
    int br = (int)((sqrtf(8.0f * t + 1.0f) - 1.0f) * 0.5f);
    while ((br + 1) * (br + 2) / 2 <= t) ++br;
    while (br * (br + 1) / 2 > t) --br;
    const int bc = t - br * (br + 1) / 2;

    const ushort* A  = Q + ((size_t)b * T_ + br * 128) * E_;
    const ushort* Bm = K + ((size_t)b * T_ + bc * 128) * E_;

    f32x4 acc[4][4];
#pragma unroll
    for (int i = 0; i < 4; ++i)
#pragma unroll
        for (int j = 0; j < 4; ++j) acc[i][j] = (f32x4){0.f, 0.f, 0.f, 0.f};

    gemm_tile64(A, E_, Bm, E_, E_ / 64, acc, As, Bs);

    const int lane = threadIdx.x & 63, wave = threadIdx.x >> 6;
    const int wr = (wave >> 1) * 64, wc = (wave & 1) * 64;
    ushort* Sb = S + (size_t)b * T_ * T_;
#pragma unroll
    for (int mi = 0; mi < 4; ++mi)
#pragma unroll
        for (int r = 0; r < 4; ++r) {
            const int row = br * 128 + wr + mi * 16 + (lane >> 4) * 4 + r;
#pragma unroll
            for (int ni = 0; ni < 4; ++ni) {
                const int col = bc * 128 + wc + ni * 16 + (lane & 15);
                float val = acc[mi][ni][r];
                if (col > row) val = -1e30f;
                Sb[(size_t)row * T_ + col] = f2bf(val);
            }
        }
}

// ---------------------------------------------------------------------------
// Stage 3: row softmax in place, 16B vector I/O. One block per row.
__global__ __launch_bounds__(256)
void softmax_kernel(ushort* __restrict__ S)
{
    const int gr = blockIdx.x;
    const int b = gr >> 11, i = gr & 2047;
    ushort* row = S + (size_t)b * T_ * T_ + (size_t)i * T_;
    const int Lpad = ((i >> 7) + 1) * 128;
    const int tid = threadIdx.x, lane = tid & 63, wave = tid >> 6;
    __shared__ float red[4];

    const int j0 = tid * 8;
    const bool act = j0 < Lpad;
    float xv[8];
    if (act) {
        int4v dv = *(const int4v*)(row + j0);
        const ushort* u = (const ushort*)&dv;
#pragma unroll
        for (int t = 0; t < 8; ++t) xv[t] = bf2f(u[t]);
    }

    float m = -1e30f;
    if (act)
#pragma unroll
        for (int t = 0; t < 8; ++t) m = fmaxf(m, xv[t]);
#pragma unroll
    for (int o = 32; o; o >>= 1) m = fmaxf(m, __shfl_xor(m, o, 64));
    if (lane == 0) red[wave] = m;
    __syncthreads();
    m = fmaxf(fmaxf(red[0], red[1]), fmaxf(red[2], red[3]));
    __syncthreads();

    float s = 0.f;
    if (act)
#pragma unroll
        for (int t = 0; t < 8; ++t) { xv[t] = __expf(xv[t] - m); s += xv[t]; }
#pragma unroll
    for (int o = 32; o; o >>= 1) s += __shfl_xor(s, o, 64);
    if (lane == 0) red[wave] = s;
    __syncthreads();
    s = red[0] + red[1] + red[2] + red[3];
    const float inv = 1.0f / s;

    if (act) {
        int4v dv;
        ushort* u = (ushort*)&dv;
#pragma unroll
        for (int t = 0; t < 8; ++t) u[t] = f2bf(xv[t] * inv);
        *(int4v*)(row + j0) = dv;
    }
}

// ---------------------------------------------------------------------------
// Stage 4: O = P @ V via V^T (NT, BK=64, 1-phase). grid (8, 16, 8). f32 out.
// br reversed so the longest causal blocks (br=15, 32 ksteps) dispatch first.
__global__ __launch_bounds__(256, 2)
void out_kernel(const ushort* __restrict__ P, const ushort* __restrict__ Vt,
                float* __restrict__ O)
{
    __shared__ ushort As[128 * 64];
    __shared__ ushort Bs[128 * 64];
    const int bc = blockIdx.x, b = blockIdx.z;
    const int br = (int)gridDim.y - 1 - (int)blockIdx.y;   // longest first
    const ushort* A  = P  + (size_t)b * T_ * T_ + (size_t)(br * 128) * T_;
    const ushort* Bm = Vt + (size_t)b * E_ * T_ + (size_t)(bc * 128) * T_;
    const int ksteps = (br + 1) * 2;   // causal K-limit, BK=64

    f32x4 acc[4][4];
#pragma unroll
    for (int i = 0; i < 4; ++i)
#pragma unroll
        for (int j = 0; j < 4; ++j) acc[i][j] = (f32x4){0.f, 0.f, 0.f, 0.f};

    gemm_tile64(A, T_, Bm, T_, ksteps, acc, As, Bs);

    const int lane = threadIdx.x & 63, wave = threadIdx.x >> 6;
    const int wr = (wave >> 1) * 64, wc = (wave & 1) * 64;
    float* Ob = O + (size_t)b * T_ * E_;
#pragma unroll
    for (int mi = 0; mi < 4; ++mi)
#pragma unroll
        for (int r = 0; r < 4; ++r) {
            const int row = br * 128 + wr + mi * 16 + (lane >> 4) * 4 + r;
#pragma unroll
            for (int ni = 0; ni < 4; ++ni) {
                const int col = bc * 128 + wc + ni * 16 + (lane & 15);
                Ob[(size_t)row * E_ + col] = acc[mi][ni][r];
            }
        }
}

// ---------------------------------------------------------------------------
extern "C" void kernel_launch(void* const* d_in, const int* in_sizes, int n_in,
                              void* d_out, int out_size, void* d_ws, size_t ws_size,
                              hipStream_t stream)
{
    const float* q  = (const float*)d_in[0];
    const float* k  = (const float*)d_in[1];
    const float* v  = (const float*)d_in[2];
    const float* Wq = (const float*)d_in[3];
    const float* Wk = (const float*)d_in[4];
    const float* Wv = (const float*)d_in[5];
    float* out = (float*)d_out;

    const size_t nQKV = (size_t)B_ * T_ * E_;      // 16,777,216 elems
    const size_t nW   = (size_t)E_ * E_;
    ushort* Q  = (ushort*)d_ws;
    ushort* K  = Q + nQKV;
    ushort* Vt = K + nQKV;
    ushort* S  = Vt + nQKV;                        // 67 MB
    ushort* Wb = S;                                // weights alias dead S region

    cvtW_kernel<<<dim3(nW / 2048, 3), 256, 0, stream>>>(Wq, Wk, Wv, Wb);
    proj_kernel<<<dim3(3072), 256, 0, stream>>>(q, k, v, Wb, Q, K, Vt);
    score_kernel<<<dim3(136, B_), 256, 0, stream>>>(Q, K, S);
    softmax_kernel<<<dim3(B_ * T_), 256, 0, stream>>>(S);
    out_kernel<<<dim3(E_ / 128, T_ / 128, B_), 256, 0, stream>>>(S, Vt, out);
}